// Round 3
// baseline (423.150 us; speedup 1.0000x reference)
//
#include <hip/hip_runtime.h>
#include <hip/hip_bf16.h>
#include <type_traits>
#include <cstdint>
#include <cstddef>

typedef __bf16 bf16_t;
typedef __attribute__((ext_vector_type(8))) __bf16 bf16x8;
typedef __attribute__((ext_vector_type(4))) float f32x4;

#define KK 8
#define BENT 4096
#define MDIM 4096
#define HIN 512
#define HENC 256
#define HCORE 512
#define HCTX 256
#define HSTATE 512
#define NPAIR (BENT*(KK-1))   // 28672

// async global->LDS, 16B per lane. LDS dest must be wave-uniform base + lane*16.
#define ASYNC16(gp, lp) \
  __builtin_amdgcn_global_load_lds((const __attribute__((address_space(1))) void*)(gp), \
                                   (__attribute__((address_space(3))) void*)(lp), 16, 0, 0)

// ---------------- activation ----------------
template<int ACT>
__device__ __forceinline__ float act_f(float v) {
  if constexpr (ACT == 1) return v > 0.f ? v : expm1f(v);        // ELU
  else if constexpr (ACT == 2) return v > 0.f ? v : 0.f;         // ReLU
  else if constexpr (ACT == 3) return 1.f / (1.f + __expf(-v));  // sigmoid
  else return v;
}

// ---------------- fp32 -> bf16x8 vector load ----------------
__device__ __forceinline__ bf16x8 load8f(const float* p) {
  const float4 f0 = ((const float4*)p)[0];
  const float4 f1 = ((const float4*)p)[1];
  bf16x8 r;
  r[0] = (bf16_t)f0.x; r[1] = (bf16_t)f0.y; r[2] = (bf16_t)f0.z; r[3] = (bf16_t)f0.w;
  r[4] = (bf16_t)f1.x; r[5] = (bf16_t)f1.y; r[6] = (bf16_t)f1.z; r[7] = (bf16_t)f1.w;
  return r;
}

// ---------------- transpose+convert: fp32 [R,C] -> bf16 [C,R] ----------------
__global__ __launch_bounds__(256)
void transpose_k(const float* __restrict__ src, bf16_t* __restrict__ dst, int R, int C) {
  __shared__ float tile[32][33];
  int tx = threadIdx.x, ty = threadIdx.y;
  int c0 = blockIdx.x * 32, r0 = blockIdx.y * 32;
  #pragma unroll
  for (int i = 0; i < 4; ++i)
    tile[ty + 8*i][tx] = src[(size_t)(r0 + ty + 8*i) * C + c0 + tx];
  __syncthreads();
  #pragma unroll
  for (int i = 0; i < 4; ++i)
    dst[(size_t)(c0 + ty + 8*i) * R + r0 + tx] = (bf16_t)tile[tx][ty + 8*i];
}

// ---------------- unified MFMA GEMM ----------------
// C = act(A @ Bt^T + bias). A: [M,K] (fp32 cvt-on-stage, or bf16 via global_load_lds).
// Bt: [N,K] bf16, row stride ldb. Block tile (32*WM) x (32*WN), 4 waves 2x2,
// wave tile (16*WM) x (16*WN) via WMxWN of 16x16x32 MFMA. BK=64.
// 1-D grid, XCD-chunked tile mapping (8 XCDs round-robin on blockIdx).
// OUTF bit0: bf16 out Cb (ldc); bit1: fp32 out Cf (ldcf).
template<int WM, int WN, int ACT, int OUTF, typename AT>
__global__ __launch_bounds__(256)
void gemm_t(const AT* __restrict__ A, const bf16_t* __restrict__ Bt,
            const float* __restrict__ bias, bf16_t* __restrict__ Cb,
            float* __restrict__ Cf, int Kd, int lda, int ldb,
            int ldc, int ldcf, int gx) {
  constexpr int TM = 32 * WM, TN = 32 * WN;
  constexpr bool A_BF16 = std::is_same<AT, __bf16>::value;
  const int tid  = threadIdx.x;
  const int lane = tid & 63;
  const int wave = tid >> 6;
  const int wm = wave >> 1, wn = wave & 1;
  const int quad = lane >> 4;
  const int l16  = lane & 15;

  // XCD-chunked tile decode: consecutive tiles (row-major, x fastest) per XCD
  const int nblk = gridDim.x;
  const int chunk = nblk >> 3;
  int tile = (chunk << 3) == nblk ? ((blockIdx.x & 7) * chunk + (blockIdx.x >> 3))
                                  : blockIdx.x;
  const int bm0 = (tile / gx) * TM;
  const int bn0 = (tile % gx) * TN;

  __shared__ __align__(16) bf16_t Alds[TM * 64];
  __shared__ __align__(16) bf16_t Blds[TN * 64];

  f32x4 acc[WM][WN];
  #pragma unroll
  for (int i = 0; i < WM; ++i)
    #pragma unroll
    for (int j = 0; j < WN; ++j)
      acc[i][j] = f32x4{0.f, 0.f, 0.f, 0.f};

  for (int k0 = 0; k0 < Kd; k0 += 64) {
    // stage A
    if constexpr (A_BF16) {
      #pragma unroll
      for (int p = 0; p < TM/32; ++p) {
        const int f = p*256 + tid;                 // 16-byte unit
        const int row = f >> 3, col = (f & 7) * 8;
        ASYNC16(A + (size_t)(bm0 + row) * lda + k0 + col, (char*)Alds + (size_t)f * 16);
      }
    } else {
      #pragma unroll
      for (int p = 0; p < TM/32; ++p) {
        const int f = p*256 + tid;
        const int row = f >> 3, col = (f & 7) * 8;
        *(bf16x8*)&Alds[row*64 + col] = load8f(A + (size_t)(bm0 + row) * lda + k0 + col);
      }
    }
    // stage B (always bf16)
    #pragma unroll
    for (int p = 0; p < TN/32; ++p) {
      const int f = p*256 + tid;
      const int row = f >> 3, col = (f & 7) * 8;
      ASYNC16(Bt + (size_t)(bn0 + row) * ldb + k0 + col, (char*)Blds + (size_t)f * 16);
    }
    __syncthreads();
    #pragma unroll
    for (int ks = 0; ks < 2; ++ks) {
      bf16x8 af[WM], bfr[WN];
      #pragma unroll
      for (int mt = 0; mt < WM; ++mt)
        af[mt] = *(const bf16x8*)&Alds[(wm*16*WM + mt*16 + l16)*64 + ks*32 + quad*8];
      #pragma unroll
      for (int nt = 0; nt < WN; ++nt)
        bfr[nt] = *(const bf16x8*)&Blds[(wn*16*WN + nt*16 + l16)*64 + ks*32 + quad*8];
      #pragma unroll
      for (int mt = 0; mt < WM; ++mt)
        #pragma unroll
        for (int nt = 0; nt < WN; ++nt)
          acc[mt][nt] = __builtin_amdgcn_mfma_f32_16x16x32_bf16(af[mt], bfr[nt], acc[mt][nt], 0, 0, 0);
    }
    __syncthreads();
  }

  // epilogue: C/D layout col = lane&15, row = quad*4 + reg  [verified m89/m91]
  #pragma unroll
  for (int mt = 0; mt < WM; ++mt)
    #pragma unroll
    for (int nt = 0; nt < WN; ++nt) {
      const int gcol = bn0 + wn*16*WN + nt*16 + l16;
      const float bv = bias ? bias[gcol] : 0.f;
      #pragma unroll
      for (int r = 0; r < 4; ++r) {
        const int grow = bm0 + wm*16*WM + mt*16 + quad*4 + r;
        float v = acc[mt][nt][r] + bv;
        v = act_f<ACT>(v);
        if constexpr (OUTF & 1) Cb[(size_t)grow * ldc  + gcol] = (bf16_t)v;
        if constexpr (OUTF & 2) Cf[(size_t)grow * ldcf + gcol] = v;
      }
    }
}

// ---------------- combine: core_out[r] = relu(U[partner] + V[self] + b_core) ----------------
__global__ __launch_bounds__(256)
void combine_k(const float* __restrict__ U, const float* __restrict__ V,
               const float* __restrict__ bc, bf16_t* __restrict__ core_out) {
  const int r = blockIdx.x * 4 + (threadIdx.x >> 6);   // pair row 0..28671
  const int lane = threadIdx.x & 63;
  const int e = r / 7, j = r - e * 7;
  const int i = e & 7;
  const int p = (j < i) ? j : j + 1;
  const int pent = (e & ~7) + p;
  const float4 u0 = ((const float4*)(U + (size_t)pent * HCORE))[lane*2];
  const float4 u1 = ((const float4*)(U + (size_t)pent * HCORE))[lane*2 + 1];
  const float4 v0 = ((const float4*)(V + (size_t)e    * HCORE))[lane*2];
  const float4 v1 = ((const float4*)(V + (size_t)e    * HCORE))[lane*2 + 1];
  const float4 b0 = ((const float4*)(bc))[lane*2];
  const float4 b1 = ((const float4*)(bc))[lane*2 + 1];
  bf16x8 o;
  float s;
  s = u0.x+v0.x+b0.x; o[0] = (bf16_t)(s > 0.f ? s : 0.f);
  s = u0.y+v0.y+b0.y; o[1] = (bf16_t)(s > 0.f ? s : 0.f);
  s = u0.z+v0.z+b0.z; o[2] = (bf16_t)(s > 0.f ? s : 0.f);
  s = u0.w+v0.w+b0.w; o[3] = (bf16_t)(s > 0.f ? s : 0.f);
  s = u1.x+v1.x+b1.x; o[4] = (bf16_t)(s > 0.f ? s : 0.f);
  s = u1.y+v1.y+b1.y; o[5] = (bf16_t)(s > 0.f ? s : 0.f);
  s = u1.z+v1.z+b1.z; o[6] = (bf16_t)(s > 0.f ? s : 0.f);
  s = u1.w+v1.w+b1.w; o[7] = (bf16_t)(s > 0.f ? s : 0.f);
  *(bf16x8*)(core_out + (size_t)r * HCORE + lane*8) = o;
}

// ---------------- attention: att[r] = sigmoid(dot(core_out[r], W_att) + b) ----------------
__global__ __launch_bounds__(256)
void att_k(const bf16_t* __restrict__ co, const float* __restrict__ Watt,
           const float* __restrict__ batt, float* __restrict__ att) {
  const int row  = blockIdx.x * 4 + (threadIdx.x >> 6);
  const int lane = threadIdx.x & 63;
  bf16x8 v = *(const bf16x8*)(co + (size_t)row * HCORE + lane * 8);
  const float4 w0 = ((const float4*)(Watt + lane * 8))[0];
  const float4 w1 = ((const float4*)(Watt + lane * 8))[1];
  float s = (float)v[0]*w0.x + (float)v[1]*w0.y + (float)v[2]*w0.z + (float)v[3]*w0.w
          + (float)v[4]*w1.x + (float)v[5]*w1.y + (float)v[6]*w1.z + (float)v[7]*w1.w;
  #pragma unroll
  for (int o = 32; o > 0; o >>= 1) s += __shfl_down(s, o, 64);
  if (lane == 0) att[row] = 1.f / (1.f + __expf(-(s + batt[0])));
}

// ---------------- effect sum + total concat ----------------
// total[e] = [state1[e] (256) | sum_j att*ctx (256) | x (512, written by GEMM1)]
__global__ __launch_bounds__(256)
void effect_k(const float* __restrict__ att, const bf16_t* __restrict__ ctx,
              const bf16_t* __restrict__ state1, bf16_t* __restrict__ total) {
  const int e = blockIdx.x;     // 0..4095
  const int c = threadIdx.x;    // 0..255
  float s = 0.f;
  #pragma unroll
  for (int j = 0; j < 7; ++j)
    s += att[e * 7 + j] * (float)ctx[(size_t)(e * 7 + j) * HCTX + c];
  total[(size_t)e * 1024 + 256 + c] = (bf16_t)s;
  total[(size_t)e * 1024 + c]       = state1[(size_t)e * HENC + c];
}

extern "C" void kernel_launch(void* const* d_in, const int* in_sizes, int n_in,
                              void* d_out, int out_size, void* d_ws, size_t ws_size,
                              hipStream_t stream) {
  const float* inputs = (const float*)d_in[0];
  const float* state  = (const float*)d_in[1];
  const float* W_in   = (const float*)d_in[2];
  const float* b_in   = (const float*)d_in[3];
  const float* W_enc  = (const float*)d_in[4];
  const float* b_enc  = (const float*)d_in[5];
  const float* W_core = (const float*)d_in[6];
  const float* b_core = (const float*)d_in[7];
  const float* W_ctx  = (const float*)d_in[8];
  const float* b_ctx  = (const float*)d_in[9];
  const float* W_att  = (const float*)d_in[10];
  const float* b_att  = (const float*)d_in[11];
  const float* W_rec  = (const float*)d_in[12];
  const float* b_rec  = (const float*)d_in[13];
  const float* W_out  = (const float*)d_in[14];
  const float* b_out  = (const float*)d_in[15];

  float* out_f       = (float*)d_out;                      // [4096,4096] fp32
  float* new_state_f = out_f + (size_t)BENT * MDIM;        // [4096,512]  fp32

  char* ws = (char*)d_ws;
  auto alloc = [&](size_t elems, size_t esz) {
    char* p = ws;
    ws += (elems * esz + 255) & ~(size_t)255;
    return p;
  };
  bf16_t* WinT   = (bf16_t*)alloc((size_t)HIN * MDIM, 2);      // [512,4096]
  bf16_t* WencT  = (bf16_t*)alloc((size_t)HENC * HSTATE, 2);   // [256,512]
  bf16_t* WcoreT = (bf16_t*)alloc((size_t)HCORE * 2*HENC, 2);  // [512,512]
  bf16_t* WctxT  = (bf16_t*)alloc((size_t)HCTX * HCORE, 2);    // [256,512]
  bf16_t* WrecT  = (bf16_t*)alloc((size_t)HSTATE * 1024, 2);   // [512,1024]
  bf16_t* WoutT  = (bf16_t*)alloc((size_t)MDIM * HSTATE, 2);   // [4096,512]
  bf16_t* state1 = (bf16_t*)alloc((size_t)BENT * HENC, 2);     // [4096,256]
  bf16_t* total  = (bf16_t*)alloc((size_t)BENT * 1024, 2);     // [4096,1024]
  bf16_t* ns_b   = (bf16_t*)alloc((size_t)BENT * HSTATE, 2);   // [4096,512]
  float*  U      = (float*)alloc((size_t)BENT * HCORE, 4);     // [4096,512] fp32
  float*  V      = (float*)alloc((size_t)BENT * HCORE, 4);     // [4096,512] fp32
  bf16_t* core_out = (bf16_t*)alloc((size_t)NPAIR * HCORE, 2); // [28672,512]
  bf16_t* context  = (bf16_t*)alloc((size_t)NPAIR * HCTX, 2);  // [28672,256]
  float*  att      = (float*)alloc((size_t)NPAIR, 4);          // [28672]

  dim3 tb(32, 8);
  // weight transposes+convert [K,N] fp32 -> [N,K] bf16
  transpose_k<<<dim3(HIN/32,   MDIM/32),   tb, 0, stream>>>(W_in,   WinT,   MDIM,   HIN);
  transpose_k<<<dim3(HENC/32,  HSTATE/32), tb, 0, stream>>>(W_enc,  WencT,  HSTATE, HENC);
  transpose_k<<<dim3(HCORE/32, (2*HENC)/32), tb, 0, stream>>>(W_core, WcoreT, 2*HENC, HCORE);
  transpose_k<<<dim3(HCTX/32,  HCORE/32),  tb, 0, stream>>>(W_ctx,  WctxT,  HCORE,  HCTX);
  transpose_k<<<dim3(HSTATE/32, 1024/32),  tb, 0, stream>>>(W_rec,  WrecT,  1024,   HSTATE);
  transpose_k<<<dim3(MDIM/32,  HSTATE/32), tb, 0, stream>>>(W_out,  WoutT,  HSTATE, MDIM);

  // state1 = relu(state @ W_enc + b_enc)   [4096x256, K=512]  tile 64x64
  gemm_t<2,2,2,1,float><<<256, 256, 0, stream>>>(
      state, WencT, b_enc, state1, nullptr, HSTATE, HSTATE, HSTATE, HENC, 0, 4);
  // x = elu(inputs @ W_in + b_in) -> total[:,512:]  [4096x512, K=4096]  tile 64x128
  gemm_t<2,4,1,1,float><<<256, 256, 0, stream>>>(
      inputs, WinT, b_in, total + 512, nullptr, MDIM, MDIM, MDIM, 1024, 0, 4);
  // U = state1 @ W_core[0:256,:]   (partner half)  [4096x512, K=256]  tile 64x128
  gemm_t<2,4,0,2,bf16_t><<<256, 256, 0, stream>>>(
      state1, WcoreT, nullptr, nullptr, U, HENC, HENC, 2*HENC, 0, HCORE, 4);
  // V = state1 @ W_core[256:512,:] (self half)
  gemm_t<2,4,0,2,bf16_t><<<256, 256, 0, stream>>>(
      state1, WcoreT + HENC, nullptr, nullptr, V, HENC, HENC, 2*HENC, 0, HCORE, 4);
  // core_out = relu(U[partner] + V[self] + b_core)
  combine_k<<<NPAIR/4, 256, 0, stream>>>(U, V, b_core, core_out);
  // context = relu(core_out @ W_ctx + b_ctx)  [28672x256, K=512]  tile 128x128
  gemm_t<4,4,2,1,bf16_t><<<448, 256, 0, stream>>>(
      core_out, WctxT, b_ctx, context, nullptr, HCORE, HCORE, HCORE, HCTX, 0, 2);
  // attention = sigmoid(core_out @ W_att + b_att)
  att_k<<<NPAIR/4, 256, 0, stream>>>(core_out, W_att, b_att, att);
  // effect sum + concat into total[:, 0:512]
  effect_k<<<BENT, 256, 0, stream>>>(att, context, state1, total);
  // new_state = sigmoid(total @ W_rec + b_rec)  [4096x512, K=1024]  tile 64x128
  gemm_t<2,4,3,3,bf16_t><<<256, 256, 0, stream>>>(
      total, WrecT, b_rec, ns_b, new_state_f, 1024, 1024, 1024, HSTATE, HSTATE, 4);
  // out = sigmoid(new_state @ W_out + b_out)  [4096x4096, K=512]  tile 128x128
  gemm_t<4,4,3,2,bf16_t><<<1024, 256, 0, stream>>>(
      ns_b, WoutT, b_out, nullptr, out_f, HSTATE, HSTATE, HSTATE, 0, MDIM, 32);
}

// Round 4
// 330.676 us; speedup vs baseline: 1.2796x; 1.2796x over previous
//
#include <hip/hip_runtime.h>
#include <hip/hip_bf16.h>
#include <type_traits>
#include <cstdint>
#include <cstddef>

typedef __bf16 bf16_t;
typedef __attribute__((ext_vector_type(8))) __bf16 bf16x8;
typedef __attribute__((ext_vector_type(4))) __bf16 bf16x4;
typedef __attribute__((ext_vector_type(4))) float f32x4;

#define KK 8
#define BENT 4096
#define MDIM 4096
#define HIN 512
#define HENC 256
#define HCORE 512
#define HCTX 256
#define HSTATE 512
#define NPAIR (BENT*(KK-1))   // 28672

// async global->LDS, 16B per lane. LDS dest must be wave-uniform base + lane*16.
#define ASYNC16(gp, lp) \
  __builtin_amdgcn_global_load_lds((const __attribute__((address_space(1))) void*)(gp), \
                                   (__attribute__((address_space(3))) void*)(lp), 16, 0, 0)

// ---------------- activation ----------------
template<int ACT>
__device__ __forceinline__ float act_f(float v) {
  if constexpr (ACT == 1) return v > 0.f ? v : expm1f(v);        // ELU
  else if constexpr (ACT == 2) return v > 0.f ? v : 0.f;         // ReLU
  else if constexpr (ACT == 3) return 1.f / (1.f + __expf(-v));  // sigmoid
  else return v;
}

// ---------------- fp32 -> bf16x8 vector load ----------------
__device__ __forceinline__ bf16x8 load8f(const float* p) {
  const float4 f0 = ((const float4*)p)[0];
  const float4 f1 = ((const float4*)p)[1];
  bf16x8 r;
  r[0] = (bf16_t)f0.x; r[1] = (bf16_t)f0.y; r[2] = (bf16_t)f0.z; r[3] = (bf16_t)f0.w;
  r[4] = (bf16_t)f1.x; r[5] = (bf16_t)f1.y; r[6] = (bf16_t)f1.z; r[7] = (bf16_t)f1.w;
  return r;
}

// ---------------- transpose+convert: fp32 [R,C] -> bf16 [C,R] ----------------
__global__ __launch_bounds__(256)
void transpose_k(const float* __restrict__ src, bf16_t* __restrict__ dst, int R, int C) {
  __shared__ float tile[32][33];
  int tx = threadIdx.x, ty = threadIdx.y;
  int c0 = blockIdx.x * 32, r0 = blockIdx.y * 32;
  #pragma unroll
  for (int i = 0; i < 4; ++i)
    tile[ty + 8*i][tx] = src[(size_t)(r0 + ty + 8*i) * C + c0 + tx];
  __syncthreads();
  #pragma unroll
  for (int i = 0; i < 4; ++i)
    dst[(size_t)(c0 + ty + 8*i) * R + r0 + tx] = (bf16_t)tile[tx][ty + 8*i];
}

// ---------------- unified MFMA GEMM (XOR-swizzled LDS, optional split-K) -------
// C = act(A @ Bt^T + bias). A: [M,K] fp32 (cvt-on-stage) or bf16 (async load).
// Bt: [N,K] bf16, row stride ldb. Block tile (32*WM)x(32*WN), 4 waves 2x2.
// LDS layout: 64-elem rows; 16B slot (row, c') holds global chunk c'^(row&7)
// -> bank-conflict-free ds_read_b128 AND contiguous async dest.
// Split-K: grid = npt * nk blocks; slice = tile/npt; A,Bt advance ksl elems,
// Cf advances pstride elems per slice.
// OUTF bit0: bf16 out Cb (ldc); bit1: fp32 out Cf (ldcf).
template<int WM, int WN, int ACT, int OUTF, typename AT>
__global__ __launch_bounds__(256)
void gemm_t(const AT* __restrict__ A, const bf16_t* __restrict__ Bt,
            const float* __restrict__ bias, bf16_t* __restrict__ Cb,
            float* __restrict__ Cf, int Kd, int lda, int ldb,
            int ldc, int ldcf, int gx, int npt, int ksl, long pstride) {
  constexpr int TM = 32 * WM, TN = 32 * WN;
  constexpr bool A_BF16 = std::is_same<AT, __bf16>::value;
  const int tid  = threadIdx.x;
  const int lane = tid & 63;
  const int wave = tid >> 6;
  const int wm = wave >> 1, wn = wave & 1;
  const int quad = lane >> 4;
  const int l16  = lane & 15;

  // XCD-chunked tile decode (grid always a multiple of 8 here)
  const int nblk = gridDim.x;
  const int chunk = nblk >> 3;
  int tile = ((chunk << 3) == nblk) ? ((blockIdx.x & 7) * chunk + (blockIdx.x >> 3))
                                    : blockIdx.x;
  const int slice = tile / npt; tile -= slice * npt;
  const int bm0 = (tile / gx) * TM;
  const int bn0 = (tile % gx) * TN;
  A  += (size_t)slice * ksl;
  Bt += (size_t)slice * ksl;
  Cf += (size_t)slice * pstride;

  __shared__ __align__(16) bf16_t Alds[TM * 64];
  __shared__ __align__(16) bf16_t Blds[TN * 64];

  f32x4 acc[WM][WN];
  #pragma unroll
  for (int i = 0; i < WM; ++i)
    #pragma unroll
    for (int j = 0; j < WN; ++j)
      acc[i][j] = f32x4{0.f, 0.f, 0.f, 0.f};

  for (int k0 = 0; k0 < Kd; k0 += 64) {
    // stage A: slot f holds global chunk (f&7)^(row&7)
    #pragma unroll
    for (int p = 0; p < TM/32; ++p) {
      const int f = p*256 + tid;
      const int row = f >> 3;
      const int cs = (f & 7) ^ (row & 7);
      if constexpr (A_BF16) {
        ASYNC16(A + (size_t)(bm0 + row) * lda + k0 + cs*8, (char*)Alds + (size_t)f * 16);
      } else {
        *(bf16x8*)((char*)Alds + (size_t)f * 16) =
            load8f(A + (size_t)(bm0 + row) * lda + k0 + cs*8);
      }
    }
    // stage B (always bf16)
    #pragma unroll
    for (int p = 0; p < TN/32; ++p) {
      const int f = p*256 + tid;
      const int row = f >> 3;
      const int cs = (f & 7) ^ (row & 7);
      ASYNC16(Bt + (size_t)(bn0 + row) * ldb + k0 + cs*8, (char*)Blds + (size_t)f * 16);
    }
    __syncthreads();
    #pragma unroll
    for (int ks = 0; ks < 2; ++ks) {
      bf16x8 af[WM], bfr[WN];
      const int xr = l16 & 7;
      #pragma unroll
      for (int mt = 0; mt < WM; ++mt) {
        const int row = wm*16*WM + mt*16 + l16;
        af[mt] = *(const bf16x8*)&Alds[row*64 + (((ks*4 + quad) ^ xr) * 8)];
      }
      #pragma unroll
      for (int nt = 0; nt < WN; ++nt) {
        const int row = wn*16*WN + nt*16 + l16;
        bfr[nt] = *(const bf16x8*)&Blds[row*64 + (((ks*4 + quad) ^ xr) * 8)];
      }
      #pragma unroll
      for (int mt = 0; mt < WM; ++mt)
        #pragma unroll
        for (int nt = 0; nt < WN; ++nt)
          acc[mt][nt] = __builtin_amdgcn_mfma_f32_16x16x32_bf16(af[mt], bfr[nt], acc[mt][nt], 0, 0, 0);
    }
    __syncthreads();
  }

  // epilogue: C/D layout col = lane&15, row = quad*4 + reg  [verified m89/m91]
  #pragma unroll
  for (int mt = 0; mt < WM; ++mt)
    #pragma unroll
    for (int nt = 0; nt < WN; ++nt) {
      const int gcol = bn0 + wn*16*WN + nt*16 + l16;
      const float bv = bias ? bias[gcol] : 0.f;
      #pragma unroll
      for (int r = 0; r < 4; ++r) {
        const int grow = bm0 + wm*16*WM + mt*16 + quad*4 + r;
        float v = acc[mt][nt][r] + bv;
        v = act_f<ACT>(v);
        if constexpr (OUTF & 1) Cb[(size_t)grow * ldc  + gcol] = (bf16_t)v;
        if constexpr (OUTF & 2) Cf[(size_t)grow * ldcf + gcol] = v;
      }
    }
}

// ---------------- split-K reduce + bias + ELU -> total[:,512:] ----------------
__global__ __launch_bounds__(256)
void reduce_elu_k(const float* __restrict__ P, const float* __restrict__ b,
                  bf16_t* __restrict__ total) {
  const int gid = blockIdx.x * 256 + threadIdx.x;   // 0..524287
  const int e = gid >> 7, c4 = (gid & 127) * 4;
  const size_t off = (size_t)e * 512 + c4;
  float4 s0 = *(const float4*)(P + off);
  float4 s1 = *(const float4*)(P + (size_t)1*BENT*512 + off);
  float4 s2 = *(const float4*)(P + (size_t)2*BENT*512 + off);
  float4 s3 = *(const float4*)(P + (size_t)3*BENT*512 + off);
  float4 bv = *(const float4*)(b + c4);
  float v0 = s0.x+s1.x+s2.x+s3.x+bv.x;
  float v1 = s0.y+s1.y+s2.y+s3.y+bv.y;
  float v2 = s0.z+s1.z+s2.z+s3.z+bv.z;
  float v3 = s0.w+s1.w+s2.w+s3.w+bv.w;
  bf16x4 o;
  o[0] = (bf16_t)act_f<1>(v0); o[1] = (bf16_t)act_f<1>(v1);
  o[2] = (bf16_t)act_f<1>(v2); o[3] = (bf16_t)act_f<1>(v3);
  *(bf16x4*)(total + (size_t)e * 1024 + 512 + c4) = o;
}

// ---------------- combine: core_out[r] = relu(UV[partner][c] + UV[self][512+c] + b_core) ----
__global__ __launch_bounds__(256)
void combine_k(const float* __restrict__ UV, const float* __restrict__ bc,
               bf16_t* __restrict__ core_out) {
  const int r = blockIdx.x * 4 + (threadIdx.x >> 6);   // pair row 0..28671
  const int lane = threadIdx.x & 63;
  const int e = r / 7, j = r - e * 7;
  const int i = e & 7;
  const int p = (j < i) ? j : j + 1;
  const int pent = (e & ~7) + p;
  const float4 u0 = ((const float4*)(UV + (size_t)pent * 1024))[lane*2];
  const float4 u1 = ((const float4*)(UV + (size_t)pent * 1024))[lane*2 + 1];
  const float4 v0 = ((const float4*)(UV + (size_t)e    * 1024 + 512))[lane*2];
  const float4 v1 = ((const float4*)(UV + (size_t)e    * 1024 + 512))[lane*2 + 1];
  const float4 b0 = ((const float4*)(bc))[lane*2];
  const float4 b1 = ((const float4*)(bc))[lane*2 + 1];
  bf16x8 o;
  float s;
  s = u0.x+v0.x+b0.x; o[0] = (bf16_t)(s > 0.f ? s : 0.f);
  s = u0.y+v0.y+b0.y; o[1] = (bf16_t)(s > 0.f ? s : 0.f);
  s = u0.z+v0.z+b0.z; o[2] = (bf16_t)(s > 0.f ? s : 0.f);
  s = u0.w+v0.w+b0.w; o[3] = (bf16_t)(s > 0.f ? s : 0.f);
  s = u1.x+v1.x+b1.x; o[4] = (bf16_t)(s > 0.f ? s : 0.f);
  s = u1.y+v1.y+b1.y; o[5] = (bf16_t)(s > 0.f ? s : 0.f);
  s = u1.z+v1.z+b1.z; o[6] = (bf16_t)(s > 0.f ? s : 0.f);
  s = u1.w+v1.w+b1.w; o[7] = (bf16_t)(s > 0.f ? s : 0.f);
  *(bf16x8*)(core_out + (size_t)r * HCORE + lane*8) = o;
}

// ---------------- attention: att[r] = sigmoid(dot(core_out[r], W_att) + b) ----------------
__global__ __launch_bounds__(256)
void att_k(const bf16_t* __restrict__ co, const float* __restrict__ Watt,
           const float* __restrict__ batt, float* __restrict__ att) {
  const int row  = blockIdx.x * 4 + (threadIdx.x >> 6);
  const int lane = threadIdx.x & 63;
  bf16x8 v = *(const bf16x8*)(co + (size_t)row * HCORE + lane * 8);
  const float4 w0 = ((const float4*)(Watt + lane * 8))[0];
  const float4 w1 = ((const float4*)(Watt + lane * 8))[1];
  float s = (float)v[0]*w0.x + (float)v[1]*w0.y + (float)v[2]*w0.z + (float)v[3]*w0.w
          + (float)v[4]*w1.x + (float)v[5]*w1.y + (float)v[6]*w1.z + (float)v[7]*w1.w;
  #pragma unroll
  for (int o = 32; o > 0; o >>= 1) s += __shfl_down(s, o, 64);
  if (lane == 0) att[row] = 1.f / (1.f + __expf(-(s + batt[0])));
}

// ---------------- effect sum + total concat ----------------
__global__ __launch_bounds__(256)
void effect_k(const float* __restrict__ att, const bf16_t* __restrict__ ctx,
              const bf16_t* __restrict__ state1, bf16_t* __restrict__ total) {
  const int e = blockIdx.x;     // 0..4095
  const int c = threadIdx.x;    // 0..255
  float s = 0.f;
  #pragma unroll
  for (int j = 0; j < 7; ++j)
    s += att[e * 7 + j] * (float)ctx[(size_t)(e * 7 + j) * HCTX + c];
  total[(size_t)e * 1024 + 256 + c] = (bf16_t)s;
  total[(size_t)e * 1024 + c]       = state1[(size_t)e * HENC + c];
}

extern "C" void kernel_launch(void* const* d_in, const int* in_sizes, int n_in,
                              void* d_out, int out_size, void* d_ws, size_t ws_size,
                              hipStream_t stream) {
  const float* inputs = (const float*)d_in[0];
  const float* state  = (const float*)d_in[1];
  const float* W_in   = (const float*)d_in[2];
  const float* b_in   = (const float*)d_in[3];
  const float* W_enc  = (const float*)d_in[4];
  const float* b_enc  = (const float*)d_in[5];
  const float* W_core = (const float*)d_in[6];
  const float* b_core = (const float*)d_in[7];
  const float* W_ctx  = (const float*)d_in[8];
  const float* b_ctx  = (const float*)d_in[9];
  const float* W_att  = (const float*)d_in[10];
  const float* b_att  = (const float*)d_in[11];
  const float* W_rec  = (const float*)d_in[12];
  const float* b_rec  = (const float*)d_in[13];
  const float* W_out  = (const float*)d_in[14];
  const float* b_out  = (const float*)d_in[15];

  float* out_f       = (float*)d_out;                      // [4096,4096] fp32
  float* new_state_f = out_f + (size_t)BENT * MDIM;        // [4096,512]  fp32

  char* ws = (char*)d_ws;
  auto alloc = [&](size_t bytes) {
    char* p = ws;
    ws += (bytes + 255) & ~(size_t)255;
    return p;
  };
  bf16_t* WinT    = (bf16_t*)alloc((size_t)HIN * MDIM * 2);     // [512,4096]
  bf16_t* WencT   = (bf16_t*)alloc((size_t)HENC * HSTATE * 2);  // [256,512]
  bf16_t* WcoreT2 = (bf16_t*)alloc((size_t)1024 * HENC * 2);    // [1024,256] packed
  bf16_t* WctxT   = (bf16_t*)alloc((size_t)HCTX * HCORE * 2);   // [256,512]
  bf16_t* WrecT   = (bf16_t*)alloc((size_t)HSTATE * 1024 * 2);  // [512,1024]
  bf16_t* WoutT   = (bf16_t*)alloc((size_t)MDIM * HSTATE * 2);  // [4096,512]
  bf16_t* state1  = (bf16_t*)alloc((size_t)BENT * HENC * 2);    // [4096,256]
  bf16_t* total   = (bf16_t*)alloc((size_t)BENT * 1024 * 2);    // [4096,1024]
  bf16_t* ns_b    = (bf16_t*)alloc((size_t)BENT * HSTATE * 2);  // [4096,512]
  float*  UV      = (float*)alloc((size_t)BENT * 1024 * 4);     // [4096,1024] fp32
  char*   S32     = alloc((size_t)4 * BENT * 512 * 4);          // P fp32 [4][4096][512] -> core_out
  float*  P        = (float*)S32;
  bf16_t* core_out = (bf16_t*)S32;                              // [28672,512] (after P dead)
  bf16_t* context  = (bf16_t*)alloc((size_t)NPAIR * HCTX * 2);  // [28672,256]
  float*  att      = (float*)alloc((size_t)NPAIR * 4);          // [28672]

  dim3 tb(32, 8);
  // weight transposes+convert [K,N] fp32 -> [N,K] bf16
  transpose_k<<<dim3(HIN/32,   MDIM/32),   tb, 0, stream>>>(W_in,  WinT,  MDIM,   HIN);
  transpose_k<<<dim3(HENC/32,  HSTATE/32), tb, 0, stream>>>(W_enc, WencT, HSTATE, HENC);
  // W_core packed: rows 0-511 = T(W_core[0:256,:]) (partner), 512-1023 = T(W_core[256:512,:]) (self)
  transpose_k<<<dim3(HCORE/32, 8), tb, 0, stream>>>(W_core,             WcoreT2,            256, HCORE);
  transpose_k<<<dim3(HCORE/32, 8), tb, 0, stream>>>(W_core + 256*HCORE, WcoreT2 + 512*256,  256, HCORE);
  transpose_k<<<dim3(HCTX/32,  HCORE/32),  tb, 0, stream>>>(W_ctx, WctxT, HCORE,  HCTX);
  transpose_k<<<dim3(HSTATE/32, 1024/32),  tb, 0, stream>>>(W_rec, WrecT, 1024,   HSTATE);
  transpose_k<<<dim3(MDIM/32,  HSTATE/32), tb, 0, stream>>>(W_out, WoutT, HSTATE, MDIM);

  // GEMM1 split-K=4: P[s] = inputs[:, s*1024:(s+1)*1024] @ W_in[s*1024:...]  [64x128 tiles]
  gemm_t<2,4,0,2,float><<<1024, 256, 0, stream>>>(
      inputs, WinT, nullptr, nullptr, P, 1024, MDIM, MDIM, 0, 512, 4, 256, 1024, (long)BENT*512);
  // x = elu(sum P + b_in) -> total[:,512:]
  reduce_elu_k<<<2048, 256, 0, stream>>>(P, b_in, total);
  // state1 = relu(state @ W_enc + b_enc)  [4096x256, K=512] tile 64x64
  gemm_t<2,2,2,1,float><<<256, 256, 0, stream>>>(
      state, WencT, b_enc, state1, nullptr, HSTATE, HSTATE, HSTATE, HENC, 0, 4, 256, 0, 0);
  // UV = state1 @ [Wc_partner | Wc_self]  [4096x1024, K=256] tile 64x128
  gemm_t<2,4,0,2,bf16_t><<<512, 256, 0, stream>>>(
      state1, WcoreT2, nullptr, nullptr, UV, HENC, HENC, HENC, 0, 1024, 8, 512, 0, 0);
  // core_out = relu(UV[partner][0:512] + UV[self][512:1024] + b_core)   (P is dead now)
  combine_k<<<NPAIR/4, 256, 0, stream>>>(UV, b_core, core_out);
  // context = relu(core_out @ W_ctx + b_ctx)  [28672x256, K=512] tile 128x64
  gemm_t<4,2,2,1,bf16_t><<<896, 256, 0, stream>>>(
      core_out, WctxT, b_ctx, context, nullptr, HCORE, HCORE, HCORE, HCTX, 0, 4, 896, 0, 0);
  // attention = sigmoid(core_out @ W_att + b_att)
  att_k<<<NPAIR/4, 256, 0, stream>>>(core_out, W_att, b_att, att);
  // effect sum + concat into total[:, 0:512]
  effect_k<<<BENT, 256, 0, stream>>>(att, context, state1, total);
  // new_state = sigmoid(total @ W_rec + b_rec)  [4096x512, K=1024] tile 64x64
  gemm_t<2,2,3,3,bf16_t><<<512, 256, 0, stream>>>(
      total, WrecT, b_rec, ns_b, new_state_f, 1024, 1024, 1024, HSTATE, HSTATE, 8, 512, 0, 0);
  // out = sigmoid(new_state @ W_out + b_out)  [4096x4096, K=512] tile 128x128
  gemm_t<4,4,3,2,bf16_t><<<1024, 256, 0, stream>>>(
      ns_b, WoutT, b_out, nullptr, out_f, HSTATE, HSTATE, HSTATE, 0, MDIM, 32, 1024, 0, 0);
}

// Round 5
// 303.347 us; speedup vs baseline: 1.3949x; 1.0901x over previous
//
#include <hip/hip_runtime.h>
#include <hip/hip_bf16.h>
#include <type_traits>
#include <cstdint>
#include <cstddef>

typedef __bf16 bf16_t;
typedef __attribute__((ext_vector_type(8))) __bf16 bf16x8;
typedef __attribute__((ext_vector_type(4))) float f32x4;

#define KK 8
#define BENT 4096
#define MDIM 4096
#define HIN 512
#define HENC 256
#define HCORE 512
#define HCTX 256
#define HSTATE 512
#define NPAIR (BENT*(KK-1))   // 28672

// ---------------- activation ----------------
template<int ACT>
__device__ __forceinline__ float act_f(float v) {
  if constexpr (ACT == 1) return v > 0.f ? v : expm1f(v);        // ELU
  else if constexpr (ACT == 2) return v > 0.f ? v : 0.f;         // ReLU
  else if constexpr (ACT == 3) return 1.f / (1.f + __expf(-v));  // sigmoid
  else return v;
}

// ---------------- batched transpose+convert: fp32 [R,C] -> bf16 [C,R] ----------------
struct TTasks {
  const float* src[7];
  bf16_t*      dst[7];
  int R[7], C[7], bstart[7];
};

__global__ __launch_bounds__(256)
void transpose_all_k(TTasks T) {
  __shared__ float tile[32][33];
  const int bid = blockIdx.x;
  int t = 0;
  #pragma unroll
  for (int q = 1; q < 7; ++q) if (bid >= T.bstart[q]) t = q;
  const float* __restrict__ src = T.src[t];
  bf16_t* __restrict__ dst = T.dst[t];
  const int R = T.R[t], C = T.C[t];
  const int lb = bid - T.bstart[t];
  const int gxt = C >> 5;
  const int c0 = (lb % gxt) * 32, r0 = (lb / gxt) * 32;
  const int tx = threadIdx.x, ty = threadIdx.y;
  #pragma unroll
  for (int i = 0; i < 4; ++i)
    tile[ty + 8*i][tx] = src[(size_t)(r0 + ty + 8*i) * C + c0 + tx];
  __syncthreads();
  #pragma unroll
  for (int i = 0; i < 4; ++i)
    dst[(size_t)(c0 + ty + 8*i) * R + r0 + tx] = (bf16_t)tile[tx][ty + 8*i];
}

// ---------------- prefetch register tile ----------------
template<typename AT> struct PF;
template<> struct PF<__bf16> { bf16x8 v; };
template<> struct PF<float>  { float4 a, b; };

__device__ __forceinline__ bf16x8 cvt8(const float4& a, const float4& b) {
  bf16x8 r;
  r[0] = (bf16_t)a.x; r[1] = (bf16_t)a.y; r[2] = (bf16_t)a.z; r[3] = (bf16_t)a.w;
  r[4] = (bf16_t)b.x; r[5] = (bf16_t)b.y; r[6] = (bf16_t)b.z; r[7] = (bf16_t)b.w;
  return r;
}

// ---------------- unified MFMA GEMM (XOR-swizzled LDS, reg-prefetch, split-K) -----
// C = act(A @ Bt^T + bias). A: [M,K] fp32 (cvt at LDS-commit) or bf16.
// Bt: [N,K] bf16, row stride ldb. Block tile (32*WM)x(32*WN), 4 waves 2x2.
// LDS: 64-elem rows; 16B slot (row,c') holds global chunk c'^(row&7) (conflict-free).
// Pipeline: regs hold tile k+1, fetched right after barrier#1 of iter k.
// Split-K: slice = tile/npt; A,Bt advance ksl elems; Cb/Cf advance pstride.
template<int WM, int WN, int ACT, int OUTF, typename AT>
__global__ __launch_bounds__(256)
void gemm_t(const AT* __restrict__ A, const bf16_t* __restrict__ Bt,
            const float* __restrict__ bias, bf16_t* __restrict__ Cb,
            float* __restrict__ Cf, int Kd, int lda, int ldb,
            int ldc, int ldcf, int gx, int npt, int ksl, size_t pstride) {
  constexpr int TM = 32 * WM, TN = 32 * WN;
  constexpr bool A_BF16 = std::is_same<AT, __bf16>::value;
  const int tid  = threadIdx.x;
  const int lane = tid & 63;
  const int wave = tid >> 6;
  const int wm = wave >> 1, wn = wave & 1;
  const int quad = lane >> 4;
  const int l16  = lane & 15;

  // XCD-chunked tile decode (grid always a multiple of 8 here)
  const int nblk = gridDim.x;
  const int chunk = nblk >> 3;
  int tile = ((chunk << 3) == nblk) ? ((blockIdx.x & 7) * chunk + (blockIdx.x >> 3))
                                    : blockIdx.x;
  const int slice = tile / npt; tile -= slice * npt;
  const int bm0 = (tile / gx) * TM;
  const int bn0 = (tile % gx) * TN;
  A  += (size_t)slice * ksl;
  Bt += (size_t)slice * ksl;
  if (Cb) Cb += slice * pstride;
  if (Cf) Cf += slice * pstride;

  __shared__ __align__(16) bf16_t Alds[TM * 64];
  __shared__ __align__(16) bf16_t Blds[TN * 64];

  f32x4 acc[WM][WN];
  #pragma unroll
  for (int i = 0; i < WM; ++i)
    #pragma unroll
    for (int j = 0; j < WN; ++j)
      acc[i][j] = f32x4{0.f, 0.f, 0.f, 0.f};

  PF<AT> pa[TM/32];
  bf16x8 pb[TN/32];

  auto fetch = [&](int k0) {
    #pragma unroll
    for (int p = 0; p < TM/32; ++p) {
      const int f = p*256 + tid;
      const int row = f >> 3;
      const int cs = (f & 7) ^ (row & 7);
      const AT* g = A + (size_t)(bm0 + row) * lda + k0 + cs*8;
      if constexpr (A_BF16) pa[p].v = *(const bf16x8*)g;
      else { pa[p].a = ((const float4*)g)[0]; pa[p].b = ((const float4*)g)[1]; }
    }
    #pragma unroll
    for (int p = 0; p < TN/32; ++p) {
      const int f = p*256 + tid;
      const int row = f >> 3;
      const int cs = (f & 7) ^ (row & 7);
      pb[p] = *(const bf16x8*)(Bt + (size_t)(bn0 + row) * ldb + k0 + cs*8);
    }
  };

  fetch(0);
  for (int k0 = 0; k0 < Kd; k0 += 64) {
    // commit prefetched regs to LDS
    #pragma unroll
    for (int p = 0; p < TM/32; ++p) {
      const int f = p*256 + tid;
      if constexpr (A_BF16) *(bf16x8*)((char*)Alds + (size_t)f*16) = pa[p].v;
      else                  *(bf16x8*)((char*)Alds + (size_t)f*16) = cvt8(pa[p].a, pa[p].b);
    }
    #pragma unroll
    for (int p = 0; p < TN/32; ++p) {
      const int f = p*256 + tid;
      *(bf16x8*)((char*)Blds + (size_t)f*16) = pb[p];
    }
    __syncthreads();
    if (k0 + 64 < Kd) fetch(k0 + 64);   // prefetch next tile (overlaps MFMA block)
    #pragma unroll
    for (int ks = 0; ks < 2; ++ks) {
      bf16x8 af[WM], bfr[WN];
      const int xr = l16 & 7;
      #pragma unroll
      for (int mt = 0; mt < WM; ++mt) {
        const int row = wm*16*WM + mt*16 + l16;
        af[mt] = *(const bf16x8*)&Alds[row*64 + (((ks*4 + quad) ^ xr) * 8)];
      }
      #pragma unroll
      for (int nt = 0; nt < WN; ++nt) {
        const int row = wn*16*WN + nt*16 + l16;
        bfr[nt] = *(const bf16x8*)&Blds[row*64 + (((ks*4 + quad) ^ xr) * 8)];
      }
      #pragma unroll
      for (int mt = 0; mt < WM; ++mt)
        #pragma unroll
        for (int nt = 0; nt < WN; ++nt)
          acc[mt][nt] = __builtin_amdgcn_mfma_f32_16x16x32_bf16(af[mt], bfr[nt], acc[mt][nt], 0, 0, 0);
    }
    __syncthreads();
  }

  // epilogue: C/D layout col = lane&15, row = quad*4 + reg  [verified m89/m91]
  #pragma unroll
  for (int mt = 0; mt < WM; ++mt)
    #pragma unroll
    for (int nt = 0; nt < WN; ++nt) {
      const int gcol = bn0 + wn*16*WN + nt*16 + l16;
      const float bv = bias ? bias[gcol] : 0.f;
      #pragma unroll
      for (int r = 0; r < 4; ++r) {
        const int grow = bm0 + wm*16*WM + mt*16 + quad*4 + r;
        float v = acc[mt][nt][r] + bv;
        v = act_f<ACT>(v);
        if constexpr (OUTF & 1) Cb[(size_t)grow * ldc  + gcol] = (bf16_t)v;
        if constexpr (OUTF & 2) Cf[(size_t)grow * ldcf + gcol] = v;
      }
    }
}

// ---------------- split-K(8) reduce + bias + ELU -> total[:,512:] ----------------
__global__ __launch_bounds__(256)
void reduce_elu_k(const bf16_t* __restrict__ P, const float* __restrict__ b,
                  bf16_t* __restrict__ total) {
  const int gid = blockIdx.x * 256 + threadIdx.x;   // 0..262143
  const int e = gid >> 6, c8 = (gid & 63) * 8;
  const float4 b0 = *(const float4*)(b + c8);
  const float4 b1 = *(const float4*)(b + c8 + 4);
  float s[8] = {b0.x, b0.y, b0.z, b0.w, b1.x, b1.y, b1.z, b1.w};
  #pragma unroll
  for (int sl = 0; sl < 8; ++sl) {
    bf16x8 v = *(const bf16x8*)(P + (size_t)sl*BENT*512 + (size_t)e*512 + c8);
    #pragma unroll
    for (int j = 0; j < 8; ++j) s[j] += (float)v[j];
  }
  bf16x8 o;
  #pragma unroll
  for (int j = 0; j < 8; ++j) o[j] = (bf16_t)act_f<1>(s[j]);
  *(bf16x8*)(total + (size_t)e * 1024 + 512 + c8) = o;
}

// ---------------- fused combine + attention ----------------
// core_out[r] = relu(UV[partner][0:512] + UV[self][512:1024] + b_core)
// att[r] = sigmoid(dot(core_out[r], W_att) + b_att)    (dot in fp32 pre-rounding)
__global__ __launch_bounds__(256)
void combine_att_k(const float* __restrict__ UV, const float* __restrict__ bc,
                   const float* __restrict__ Watt, const float* __restrict__ batt,
                   bf16_t* __restrict__ core_out, float* __restrict__ att) {
  const int r = blockIdx.x * 4 + (threadIdx.x >> 6);   // pair row 0..28671
  const int lane = threadIdx.x & 63;
  const int e = r / 7, j = r - e * 7;
  const int i = e & 7;
  const int p = (j < i) ? j : j + 1;
  const int pent = (e & ~7) + p;
  const float4 u0 = ((const float4*)(UV + (size_t)pent * 1024))[lane*2];
  const float4 u1 = ((const float4*)(UV + (size_t)pent * 1024))[lane*2 + 1];
  const float4 v0 = ((const float4*)(UV + (size_t)e    * 1024 + 512))[lane*2];
  const float4 v1 = ((const float4*)(UV + (size_t)e    * 1024 + 512))[lane*2 + 1];
  const float4 b0 = ((const float4*)(bc))[lane*2];
  const float4 b1 = ((const float4*)(bc))[lane*2 + 1];
  const float4 w0 = ((const float4*)(Watt + lane*8))[0];
  const float4 w1 = ((const float4*)(Watt + lane*8))[1];
  float s[8];
  s[0] = u0.x+v0.x+b0.x; s[1] = u0.y+v0.y+b0.y;
  s[2] = u0.z+v0.z+b0.z; s[3] = u0.w+v0.w+b0.w;
  s[4] = u1.x+v1.x+b1.x; s[5] = u1.y+v1.y+b1.y;
  s[6] = u1.z+v1.z+b1.z; s[7] = u1.w+v1.w+b1.w;
  bf16x8 o;
  #pragma unroll
  for (int q = 0; q < 8; ++q) { s[q] = s[q] > 0.f ? s[q] : 0.f; o[q] = (bf16_t)s[q]; }
  *(bf16x8*)(core_out + (size_t)r * HCORE + lane*8) = o;
  float d = s[0]*w0.x + s[1]*w0.y + s[2]*w0.z + s[3]*w0.w
          + s[4]*w1.x + s[5]*w1.y + s[6]*w1.z + s[7]*w1.w;
  #pragma unroll
  for (int off = 32; off > 0; off >>= 1) d += __shfl_down(d, off, 64);
  if (lane == 0) att[r] = 1.f / (1.f + __expf(-(d + batt[0])));
}

// ---------------- effect sum + total concat ----------------
__global__ __launch_bounds__(256)
void effect_k(const float* __restrict__ att, const bf16_t* __restrict__ ctx,
              const bf16_t* __restrict__ state1, bf16_t* __restrict__ total) {
  const int e = blockIdx.x;     // 0..4095
  const int c = threadIdx.x;    // 0..255
  float s = 0.f;
  #pragma unroll
  for (int j = 0; j < 7; ++j)
    s += att[e * 7 + j] * (float)ctx[(size_t)(e * 7 + j) * HCTX + c];
  total[(size_t)e * 1024 + 256 + c] = (bf16_t)s;
  total[(size_t)e * 1024 + c]       = state1[(size_t)e * HENC + c];
}

extern "C" void kernel_launch(void* const* d_in, const int* in_sizes, int n_in,
                              void* d_out, int out_size, void* d_ws, size_t ws_size,
                              hipStream_t stream) {
  const float* inputs = (const float*)d_in[0];
  const float* state  = (const float*)d_in[1];
  const float* W_in   = (const float*)d_in[2];
  const float* b_in   = (const float*)d_in[3];
  const float* W_enc  = (const float*)d_in[4];
  const float* b_enc  = (const float*)d_in[5];
  const float* W_core = (const float*)d_in[6];
  const float* b_core = (const float*)d_in[7];
  const float* W_ctx  = (const float*)d_in[8];
  const float* b_ctx  = (const float*)d_in[9];
  const float* W_att  = (const float*)d_in[10];
  const float* b_att  = (const float*)d_in[11];
  const float* W_rec  = (const float*)d_in[12];
  const float* b_rec  = (const float*)d_in[13];
  const float* W_out  = (const float*)d_in[14];
  const float* b_out  = (const float*)d_in[15];

  float* out_f       = (float*)d_out;                      // [4096,4096] fp32
  float* new_state_f = out_f + (size_t)BENT * MDIM;        // [4096,512]  fp32

  char* ws = (char*)d_ws;
  auto alloc = [&](size_t bytes) {
    char* p = ws;
    ws += (bytes + 255) & ~(size_t)255;
    return p;
  };
  bf16_t* WinT    = (bf16_t*)alloc((size_t)HIN * MDIM * 2);     // [512,4096]
  bf16_t* WencT   = (bf16_t*)alloc((size_t)HENC * HSTATE * 2);  // [256,512]
  bf16_t* WcoreT2 = (bf16_t*)alloc((size_t)1024 * HENC * 2);    // [1024,256] packed
  bf16_t* WctxT   = (bf16_t*)alloc((size_t)HCTX * HCORE * 2);   // [256,512]
  bf16_t* WrecT   = (bf16_t*)alloc((size_t)HSTATE * 1024 * 2);  // [512,1024]
  bf16_t* WoutT   = (bf16_t*)alloc((size_t)MDIM * HSTATE * 2);  // [4096,512]
  bf16_t* state1  = (bf16_t*)alloc((size_t)BENT * HENC * 2);    // [4096,256]
  bf16_t* total   = (bf16_t*)alloc((size_t)BENT * 1024 * 2);    // [4096,1024]
  bf16_t* ns_b    = (bf16_t*)alloc((size_t)BENT * HSTATE * 2);  // [4096,512]
  float*  UV      = (float*)alloc((size_t)BENT * 1024 * 4);     // [4096,1024] fp32
  char*   S32     = alloc((size_t)8 * BENT * 512 * 2);          // P bf16 [8][4096][512] -> core_out
  bf16_t* P        = (bf16_t*)S32;
  bf16_t* core_out = (bf16_t*)S32;                              // [28672,512] (after P dead)
  bf16_t* context  = (bf16_t*)alloc((size_t)NPAIR * HCTX * 2);  // [28672,256]
  float*  att      = (float*)alloc((size_t)NPAIR * 4);          // [28672]

  // ---- one batched transpose kernel for all 7 weight transposes ----
  TTasks T;
  T.src[0]=W_in;              T.dst[0]=WinT;           T.R[0]=MDIM;  T.C[0]=HIN;   // 2048 blocks
  T.src[1]=W_enc;             T.dst[1]=WencT;          T.R[1]=HSTATE;T.C[1]=HENC;  // 128
  T.src[2]=W_core;            T.dst[2]=WcoreT2;        T.R[2]=256;   T.C[2]=HCORE; // 128
  T.src[3]=W_core+256*HCORE;  T.dst[3]=WcoreT2+512*256;T.R[3]=256;   T.C[3]=HCORE; // 128
  T.src[4]=W_ctx;             T.dst[4]=WctxT;          T.R[4]=HCORE; T.C[4]=HCTX;  // 128
  T.src[5]=W_rec;             T.dst[5]=WrecT;          T.R[5]=1024;  T.C[5]=HSTATE;// 512
  T.src[6]=W_out;             T.dst[6]=WoutT;          T.R[6]=HSTATE;T.C[6]=MDIM;  // 2048
  int bs = 0;
  for (int t = 0; t < 7; ++t) {
    T.bstart[t] = bs;
    bs += (T.C[t] >> 5) * (T.R[t] >> 5);
  }
  transpose_all_k<<<bs, dim3(32, 8), 0, stream>>>(T);

  // GEMM1 split-K=8, 128x128 tiles: P[s] = inputs[:, s*512:] @ W_in-slice  (bf16 partials)
  gemm_t<4,4,0,1,float><<<1024, 256, 0, stream>>>(
      inputs, WinT, nullptr, P, nullptr, 512, MDIM, MDIM, 512, 0, 4, 128, 512, (size_t)BENT*512);
  // x = elu(sum_s P[s] + b_in) -> total[:,512:]
  reduce_elu_k<<<1024, 256, 0, stream>>>(P, b_in, total);
  // state1 = relu(state @ W_enc + b_enc)  [4096x256, K=512] tile 64x64
  gemm_t<2,2,2,1,float><<<256, 256, 0, stream>>>(
      state, WencT, b_enc, state1, nullptr, HSTATE, HSTATE, HSTATE, HENC, 0, 4, 256, 0, 0);
  // UV = state1 @ [Wc_partner | Wc_self]  [4096x1024, K=256] tile 64x128
  gemm_t<2,4,0,2,bf16_t><<<512, 256, 0, stream>>>(
      state1, WcoreT2, nullptr, nullptr, UV, HENC, HENC, HENC, 0, 1024, 8, 512, 0, 0);
  // core_out = relu(UV[partner] + UV[self] + b_core); att fused   (P dead now)
  combine_att_k<<<NPAIR/4, 256, 0, stream>>>(UV, b_core, W_att, b_att, core_out, att);
  // context = relu(core_out @ W_ctx + b_ctx)  [28672x256, K=512] tile 128x64
  gemm_t<4,2,2,1,bf16_t><<<896, 256, 0, stream>>>(
      core_out, WctxT, b_ctx, context, nullptr, HCORE, HCORE, HCORE, HCTX, 0, 4, 896, 0, 0);
  // effect sum + concat into total[:, 0:512]
  effect_k<<<BENT, 256, 0, stream>>>(att, context, state1, total);
  // new_state = sigmoid(total @ W_rec + b_rec)  [4096x512, K=1024] tile 64x64
  gemm_t<2,2,3,3,bf16_t><<<512, 256, 0, stream>>>(
      total, WrecT, b_rec, ns_b, new_state_f, 1024, 1024, 1024, HSTATE, HSTATE, 8, 512, 0, 0);
  // out = sigmoid(new_state @ W_out + b_out)  [4096x4096, K=512] tile 128x128
  gemm_t<4,4,3,2,bf16_t><<<1024, 256, 0, stream>>>(
      ns_b, WoutT, b_out, nullptr, out_f, HSTATE, HSTATE, HSTATE, 0, MDIM, 32, 1024, 0, 0);
}